// Round 3
// baseline (154.282 us; speedup 1.0000x reference)
//
#include <hip/hip_runtime.h>

#define B_ 4
#define C_ 256
#define H_ 128
#define W_ 128
#define Q_ 100

// ---------------------------------------------------------------------------
// Kernel 1: row cumsum (along x) fused with NCHW -> NHWC transpose.
// Block = (b, y, cb); cb selects 64 channels. 256 threads.
// float4 global loads/stores (16B/lane). LDS tile [64][129] (+1 pad).
// Output: Prow[((b*H + y)*W + x)*C + c] = sum_{x'<=x} x[b,c,y,x'].
// ---------------------------------------------------------------------------
__global__ __launch_bounds__(256) void rowscan_kernel(const float4* __restrict__ x4,
                                                      float4* __restrict__ P4) {
    __shared__ float tile[64][129];
    const int blk = blockIdx.x;            // b*512 + y*4 + cb
    const int cb  = blk & 3;
    const int y   = (blk >> 2) & 127;
    const int b   = blk >> 9;
    const int c0  = cb * 64;
    const int tid = threadIdx.x;

    const float4* src = x4 + ((size_t)((b * C_ + c0) * H_ + y) * W_) / 4;
    #pragma unroll
    for (int i = 0; i < 8; ++i) {
        int idx = i * 256 + tid;
        int cl  = idx >> 5;          // 0..63
        int x4i = idx & 31;          // 0..31
        float4 v = src[(size_t)cl * (H_ * W_ / 4) + x4i];
        tile[cl][4 * x4i + 0] = v.x;
        tile[cl][4 * x4i + 1] = v.y;
        tile[cl][4 * x4i + 2] = v.z;
        tile[cl][4 * x4i + 3] = v.w;
    }
    __syncthreads();

    // Wave-parallel inclusive scan of each 128-wide row (2 elems/lane).
    const int wave = tid >> 6, lane = tid & 63;
    for (int r = wave; r < 64; r += 4) {
        float v0 = tile[r][2 * lane];
        float v1 = tile[r][2 * lane + 1];
        float s  = v0 + v1;
        #pragma unroll
        for (int d = 1; d < 64; d <<= 1) {
            float t = __shfl_up(s, d);
            if (lane >= d) s += t;
        }
        float excl = s - (v0 + v1);
        tile[r][2 * lane]     = excl + v0;
        tile[r][2 * lane + 1] = s;
    }
    __syncthreads();

    float4* dst = P4 + ((size_t)(b * H_ + y) * W_) * (C_ / 4);
    #pragma unroll
    for (int i = 0; i < 8; ++i) {
        int idx = i * 256 + tid;
        int cg  = idx & 15;          // 16 groups of 4 channels
        int xx  = idx >> 4;          // 0..127
        float4 o;
        o.x = tile[4 * cg + 0][xx];
        o.y = tile[4 * cg + 1][xx];
        o.z = tile[4 * cg + 2][xx];
        o.w = tile[4 * cg + 3][xx];
        dst[(size_t)xx * (C_ / 4) + (c0 >> 2) + cg] = o;
    }
}

// ---------------------------------------------------------------------------
// Kernel 2: fused y-accumulate + gather. No column SAT pass.
// Grid = (b, q, k) where k is the y-bin: 4*100*7 = 2800 blocks x 64 threads.
// bin(k,ox) = sum_{y in [ys_k, ye_k)} ( Prow[y][xe_ox-1] - Prow[y][xs_ox-1] )
// (x-bins' lo term dropped when xs==0). Lane owns 4 channels (float4), so
// each load is 64 lanes x 16B = 1KB coalesced from the L3-resident Prow.
// 14 independent loads in flight per row; acc[7] float4 in registers.
// ---------------------------------------------------------------------------
__global__ __launch_bounds__(64) void gather_kernel(const float4* __restrict__ P4,
                                                    const int* __restrict__ rois,
                                                    float* __restrict__ out) {
    const int k    = blockIdx.x % 7;
    const int bq   = blockIdx.x / 7;
    const int b    = bq / Q_;
    const int lane = threadIdx.x;

    const int* r = rois + (size_t)bq * 5;
    const int x1 = r[1], y1 = r[2], x2 = r[3], y2 = r[4];
    const int Lx = x2 - x1, Ly = y2 - y1;

    const int ys = y1 + (k * Ly) / 7;
    const int ye = y1 + ((k + 1) * Ly + 6) / 7;

    int xso[7], xeo[7], xw[7];
    #pragma unroll
    for (int ox = 0; ox < 7; ++ox) {
        int xs = x1 + (ox * Lx) / 7;
        int xe = x1 + ((ox + 1) * Lx + 6) / 7;
        xso[ox] = (xs - 1) * (C_ / 4);   // xs>=1 for ox>=1; ox==0 guarded below
        xeo[ox] = (xe - 1) * (C_ / 4);
        xw[ox]  = xe - xs;
    }

    float4 acc[7];
    #pragma unroll
    for (int ox = 0; ox < 7; ++ox) acc[ox] = make_float4(0.f, 0.f, 0.f, 0.f);

    const float4* rowp = P4 + ((size_t)(b * H_ + ys) * W_) * (C_ / 4) + lane;
    const size_t rstride = (size_t)W_ * (C_ / 4);

    if (x1 > 0) {
        for (int y = ys; y < ye; ++y, rowp += rstride) {
            float4 hi[7], lo[7];
            #pragma unroll
            for (int ox = 0; ox < 7; ++ox) hi[ox] = rowp[xeo[ox]];
            #pragma unroll
            for (int ox = 0; ox < 7; ++ox) lo[ox] = rowp[xso[ox]];
            #pragma unroll
            for (int ox = 0; ox < 7; ++ox) {
                acc[ox].x += hi[ox].x - lo[ox].x;
                acc[ox].y += hi[ox].y - lo[ox].y;
                acc[ox].z += hi[ox].z - lo[ox].z;
                acc[ox].w += hi[ox].w - lo[ox].w;
            }
        }
    } else {
        for (int y = ys; y < ye; ++y, rowp += rstride) {
            float4 hi[7], lo[6];
            #pragma unroll
            for (int ox = 0; ox < 7; ++ox) hi[ox] = rowp[xeo[ox]];
            #pragma unroll
            for (int ox = 1; ox < 7; ++ox) lo[ox - 1] = rowp[xso[ox]];
            acc[0].x += hi[0].x; acc[0].y += hi[0].y;
            acc[0].z += hi[0].z; acc[0].w += hi[0].w;
            #pragma unroll
            for (int ox = 1; ox < 7; ++ox) {
                acc[ox].x += hi[ox].x - lo[ox - 1].x;
                acc[ox].y += hi[ox].y - lo[ox - 1].y;
                acc[ox].z += hi[ox].z - lo[ox - 1].z;
                acc[ox].w += hi[ox].w - lo[ox - 1].w;
            }
        }
    }

    // out[((b*Q+q)*C + c)*49 + k*7 + ox], c = 4*lane + j
    const int hbin = ye - ys;
    float* ob = out + (size_t)bq * (C_ * 49) + (size_t)(4 * lane) * 49 + k * 7;
    #pragma unroll
    for (int ox = 0; ox < 7; ++ox) {
        float area = (float)(hbin * xw[ox]);
        ob[0 * 49 + ox] = acc[ox].x / area;
        ob[1 * 49 + ox] = acc[ox].y / area;
        ob[2 * 49 + ox] = acc[ox].z / area;
        ob[3 * 49 + ox] = acc[ox].w / area;
    }
}

extern "C" void kernel_launch(void* const* d_in, const int* in_sizes, int n_in,
                              void* d_out, int out_size, void* d_ws, size_t ws_size,
                              hipStream_t stream) {
    const float* x    = (const float*)d_in[0];
    const int*   rois = (const int*)d_in[1];
    float*       outp = (float*)d_out;
    float*       P    = (float*)d_ws;   // 64 MiB NHWC row-prefix buffer

    rowscan_kernel<<<B_ * H_ * 4, 256, 0, stream>>>((const float4*)x, (float4*)P);
    gather_kernel<<<B_ * Q_ * 7, 64, 0, stream>>>((const float4*)P, rois, outp);
}

// Round 4
// 131.141 us; speedup vs baseline: 1.1765x; 1.1765x over previous
//
#include <hip/hip_runtime.h>

#define B_ 4
#define C_ 256
#define H_ 128
#define W_ 128
#define Q_ 100

// ---------------------------------------------------------------------------
// Kernel 1: row cumsum (along x) fused with NCHW -> NHWC transpose.
// Block = (b, y, cb); cb selects 64 channels. 256 threads.
// float4 global loads/stores (16B/lane). LDS tile [64][129] (+1 pad).
// Output: Prow[((b*H + y)*W + x)*C + c] = sum_{x'<=x} x[b,c,y,x'].
// ---------------------------------------------------------------------------
__global__ __launch_bounds__(256) void rowscan_kernel(const float4* __restrict__ x4,
                                                      float4* __restrict__ P4) {
    __shared__ float tile[64][129];
    const int blk = blockIdx.x;            // b*512 + y*4 + cb
    const int cb  = blk & 3;
    const int y   = (blk >> 2) & 127;
    const int b   = blk >> 9;
    const int c0  = cb * 64;
    const int tid = threadIdx.x;

    const float4* src = x4 + ((size_t)((b * C_ + c0) * H_ + y) * W_) / 4;
    #pragma unroll
    for (int i = 0; i < 8; ++i) {
        int idx = i * 256 + tid;
        int cl  = idx >> 5;          // 0..63
        int x4i = idx & 31;          // 0..31
        float4 v = src[(size_t)cl * (H_ * W_ / 4) + x4i];
        tile[cl][4 * x4i + 0] = v.x;
        tile[cl][4 * x4i + 1] = v.y;
        tile[cl][4 * x4i + 2] = v.z;
        tile[cl][4 * x4i + 3] = v.w;
    }
    __syncthreads();

    // Wave-parallel inclusive scan of each 128-wide row (2 elems/lane).
    const int wave = tid >> 6, lane = tid & 63;
    for (int r = wave; r < 64; r += 4) {
        float v0 = tile[r][2 * lane];
        float v1 = tile[r][2 * lane + 1];
        float s  = v0 + v1;
        #pragma unroll
        for (int d = 1; d < 64; d <<= 1) {
            float t = __shfl_up(s, d);
            if (lane >= d) s += t;
        }
        float excl = s - (v0 + v1);
        tile[r][2 * lane]     = excl + v0;
        tile[r][2 * lane + 1] = s;
    }
    __syncthreads();

    float4* dst = P4 + ((size_t)(b * H_ + y) * W_) * (C_ / 4);
    #pragma unroll
    for (int i = 0; i < 8; ++i) {
        int idx = i * 256 + tid;
        int cg  = idx & 15;          // 16 groups of 4 channels
        int xx  = idx >> 4;          // 0..127
        float4 o;
        o.x = tile[4 * cg + 0][xx];
        o.y = tile[4 * cg + 1][xx];
        o.z = tile[4 * cg + 2][xx];
        o.w = tile[4 * cg + 3][xx];
        dst[(size_t)xx * (C_ / 4) + (c0 >> 2) + cg] = o;
    }
}

// ---------------------------------------------------------------------------
// Kernel 2: fused y-accumulate + gather, v2.
// Block = (bq, cg): cg selects 64 channels; 1600 blocks x 256 threads
// (6400 waves, ~25/CU). Lane owns 1 channel (4B loads -> 256B/wave/point).
// Wave w handles y-bins {w, w+4}: 7 register accumulators, 14 independent
// loads per row in flight. Results staged in LDS obuf[64][49] (stride 49,
// <=2-way banks = free), then ONE contiguous 12.5KB float4 writeback
// -> no partial-cacheline write amplification.
// ---------------------------------------------------------------------------
__global__ __launch_bounds__(256) void gather_kernel(const float* __restrict__ P,
                                                     const int* __restrict__ rois,
                                                     float* __restrict__ out) {
    __shared__ float obuf[64 * 49];

    const int cg   = blockIdx.x & 3;
    const int bq   = blockIdx.x >> 2;
    const int b    = bq / Q_;
    const int tid  = threadIdx.x;
    const int wv   = tid >> 6;
    const int lane = tid & 63;
    const int c    = cg * 64 + lane;

    const int* r = rois + (size_t)bq * 5;
    const int x1 = r[1], y1 = r[2], x2 = r[3], y2 = r[4];
    const int Lx = x2 - x1, Ly = y2 - y1;

    // x-bin edges (same for all y-bins)
    int xso[7], xeo[7], xw[7];
    #pragma unroll
    for (int ox = 0; ox < 7; ++ox) {
        int xs = x1 + (ox * Lx) / 7;             // floor
        int xe = x1 + ((ox + 1) * Lx + 6) / 7;   // ceil
        xso[ox] = (xs - 1) * C_;                 // xs>=1 for ox>=1
        xeo[ox] = (xe - 1) * C_;
        xw[ox]  = xe - xs;
    }

    const float* Sb = P + (size_t)b * (H_ * W_ * C_) + c;
    const size_t rstride = (size_t)W_ * C_;

    #pragma unroll
    for (int t = 0; t < 2; ++t) {
        const int k = wv + t * 4;
        if (k < 7) {
            const int ys = y1 + (k * Ly) / 7;
            const int ye = y1 + ((k + 1) * Ly + 6) / 7;

            float acc[7];
            #pragma unroll
            for (int ox = 0; ox < 7; ++ox) acc[ox] = 0.f;

            const float* rowp = Sb + (size_t)ys * rstride;
            if (x1 > 0) {
                for (int y = ys; y < ye; ++y, rowp += rstride) {
                    float hi[7], lo[7];
                    #pragma unroll
                    for (int ox = 0; ox < 7; ++ox) hi[ox] = rowp[xeo[ox]];
                    #pragma unroll
                    for (int ox = 0; ox < 7; ++ox) lo[ox] = rowp[xso[ox]];
                    #pragma unroll
                    for (int ox = 0; ox < 7; ++ox) acc[ox] += hi[ox] - lo[ox];
                }
            } else {
                for (int y = ys; y < ye; ++y, rowp += rstride) {
                    float hi[7], lo[6];
                    #pragma unroll
                    for (int ox = 0; ox < 7; ++ox) hi[ox] = rowp[xeo[ox]];
                    #pragma unroll
                    for (int ox = 1; ox < 7; ++ox) lo[ox - 1] = rowp[xso[ox]];
                    acc[0] += hi[0];
                    #pragma unroll
                    for (int ox = 1; ox < 7; ++ox) acc[ox] += hi[ox] - lo[ox - 1];
                }
            }

            const float hinv = 1.f / (float)(ye - ys);
            #pragma unroll
            for (int ox = 0; ox < 7; ++ox)
                obuf[lane * 49 + k * 7 + ox] = acc[ox] * hinv / (float)xw[ox];
        }
    }
    __syncthreads();

    // Contiguous writeback: out region for (bq, cg) = 64 channels x 49 floats.
    const float4* ob4 = (const float4*)obuf;
    float4* dst = (float4*)(out + ((size_t)bq * C_ + cg * 64) * 49);
    #pragma unroll
    for (int i = 0; i < 3; ++i) dst[i * 256 + tid] = ob4[i * 256 + tid];
    if (tid < 16) dst[768 + tid] = ob4[768 + tid];
}

extern "C" void kernel_launch(void* const* d_in, const int* in_sizes, int n_in,
                              void* d_out, int out_size, void* d_ws, size_t ws_size,
                              hipStream_t stream) {
    const float* x    = (const float*)d_in[0];
    const int*   rois = (const int*)d_in[1];
    float*       outp = (float*)d_out;
    float*       P    = (float*)d_ws;   // 64 MiB NHWC row-prefix buffer

    rowscan_kernel<<<B_ * H_ * 4, 256, 0, stream>>>((const float4*)x, (float4*)P);
    gather_kernel<<<B_ * Q_ * 4, 256, 0, stream>>>(P, rois, outp);
}

// Round 5
// 131.083 us; speedup vs baseline: 1.1770x; 1.0004x over previous
//
#include <hip/hip_runtime.h>

#define B_ 4
#define C_ 256
#define H_ 128
#define W_ 128
#define Q_ 100

// ---------------------------------------------------------------------------
// Single fused kernel. Block = (b, c): one channel's 128x128 image.
//  Phase 1: coalesced 64 KB load NCHW image -> LDS (16 float4 / thread).
//  Phase 2: row-wise inclusive scan (x) — wave-parallel shuffle scan,
//           2 elems/lane, 32 rows/wave.
//  Phase 3: column-wise inclusive scan (y) — thread per column, register
//           accumulator (LDS reads pipeline; add chain is VALU-only).
//  Phase 4: all 100 q x 49 bins for this channel: 4 LDS reads + 1 div each,
//           write straight to out (49-float contiguous runs per (q,c)).
// LDS = exactly 64 KiB -> 2 blocks/CU, 8 waves/CU.
// No workspace use at all (d_ws untouched).
// ---------------------------------------------------------------------------
__global__ __launch_bounds__(256) void roipool_kernel(const float4* __restrict__ x4,
                                                      const int* __restrict__ rois,
                                                      float* __restrict__ out) {
    __shared__ float sat[H_ * W_];   // 64 KiB: one channel image -> inclusive 2D SAT

    const int c   = blockIdx.x & 255;
    const int b   = blockIdx.x >> 8;
    const int tid = threadIdx.x;

    // ---- Phase 1: load channel image (64 KB, fully coalesced) ----
    const float4* src = x4 + (size_t)(b * C_ + c) * (H_ * W_ / 4);
    float4* s4 = (float4*)sat;
    #pragma unroll
    for (int i = 0; i < 16; ++i)
        s4[i * 256 + tid] = src[i * 256 + tid];
    __syncthreads();

    // ---- Phase 2: row-wise inclusive scan (x direction) ----
    const int wave = tid >> 6, lane = tid & 63;
    for (int r = wave; r < H_; r += 4) {
        float v0 = sat[r * W_ + 2 * lane];
        float v1 = sat[r * W_ + 2 * lane + 1];
        float s  = v0 + v1;
        #pragma unroll
        for (int d = 1; d < 64; d <<= 1) {
            float t = __shfl_up(s, d);
            if (lane >= d) s += t;
        }
        float excl = s - (v0 + v1);
        sat[r * W_ + 2 * lane]     = excl + v0;
        sat[r * W_ + 2 * lane + 1] = excl + v0 + v1;
    }
    __syncthreads();

    // ---- Phase 3: column-wise inclusive scan (y direction) ----
    if (tid < W_) {
        float acc = 0.f;
        #pragma unroll 8
        for (int y = 0; y < H_; ++y) {
            acc += sat[y * W_ + tid];
            sat[y * W_ + tid] = acc;
        }
    }
    __syncthreads();

    // ---- Phase 4: gather all (q, bin) for this (b, c) ----
    // S(a,e) [reference's zero-padded SAT] = (a>0 && e>0) ? sat[a-1][e-1] : 0.
    const int* rb = rois + (size_t)b * Q_ * 5;
    for (int t = tid; t < Q_ * 49; t += 256) {
        const int q   = t / 49;
        const int bin = t - q * 49;
        const int oy  = bin / 7;
        const int ox  = bin - oy * 7;

        const int x1 = rb[q * 5 + 1];
        const int y1 = rb[q * 5 + 2];
        const int Lx = rb[q * 5 + 3] - x1;
        const int Ly = rb[q * 5 + 4] - y1;

        const int ys = y1 + (oy * Ly) / 7;               // floor
        const int ye = y1 + ((oy + 1) * Ly + 6) / 7;     // ceil
        const int xs = x1 + (ox * Lx) / 7;               // floor
        const int xe = x1 + ((ox + 1) * Lx + 6) / 7;     // ceil

        const float s11 = sat[(ye - 1) * W_ + (xe - 1)];
        const float s01 = (ys > 0) ? sat[(ys - 1) * W_ + (xe - 1)] : 0.f;
        const float s10 = (xs > 0) ? sat[(ye - 1) * W_ + (xs - 1)] : 0.f;
        const float s00 = (ys > 0 && xs > 0) ? sat[(ys - 1) * W_ + (xs - 1)] : 0.f;

        const float area = (float)((ye - ys) * (xe - xs));
        out[(((size_t)(b * Q_ + q)) * C_ + c) * 49 + bin] =
            (s11 - s01 - s10 + s00) / area;
    }
}

extern "C" void kernel_launch(void* const* d_in, const int* in_sizes, int n_in,
                              void* d_out, int out_size, void* d_ws, size_t ws_size,
                              hipStream_t stream) {
    const float* x    = (const float*)d_in[0];
    const int*   rois = (const int*)d_in[1];
    float*       outp = (float*)d_out;

    roipool_kernel<<<B_ * C_, 256, 0, stream>>>((const float4*)x, rois, outp);
}

// Round 7
// 118.780 us; speedup vs baseline: 1.2989x; 1.1036x over previous
//
#include <hip/hip_runtime.h>

#define B_ 4
#define C_ 256
#define H_ 128
#define W_ 128
#define Q_ 100
#define WP_ 132                 // padded row stride in words: bank = (4y + x) % 32

// ---------------------------------------------------------------------------
// Single fused kernel. Block = (b, c): one channel's 128x128 image -> SAT in
// LDS -> all 100*49 outputs. 512 threads (8 waves), LDS ~68KB -> 2 blocks/CU
// (16 waves/CU).
//  Phase 1: coalesced 64 KB load NCHW image -> padded LDS (8 float4/thread).
//  Phase 2: row-wise inclusive scan; float2 per lane + shuffle scan.
//  Phase 3: column scan split into 4 quarter-scans (chain 32) + parallel
//           fixup with quarter-total prefix (24 parallel iters).
//  Phase 4: 4900 bins: 4 LDS reads (padding -> conflict-free) + div, write
//           straight to out.
// ---------------------------------------------------------------------------
__global__ __launch_bounds__(512, 4) void roipool_kernel(const float4* __restrict__ x4,
                                                         const int* __restrict__ rois,
                                                         float* __restrict__ out) {
    __shared__ float sat[H_ * WP_];    // 67584 B
    __shared__ float qt[4][W_];        // 2 KB quarter totals -> offsets

    const int c   = blockIdx.x & 255;
    const int b   = blockIdx.x >> 8;
    const int tid = threadIdx.x;

    // ---- Phase 1: load channel image (64 KB, coalesced), padded rows ----
    const float4* src = x4 + (size_t)(b * C_ + c) * (H_ * W_ / 4);
    float4* s4 = (float4*)sat;
    #pragma unroll
    for (int i = 0; i < 8; ++i) {
        int idx  = i * 512 + tid;       // 0..4095 float4s
        int row  = idx >> 5;            // 0..127
        int col4 = idx & 31;            // 0..31
        s4[row * (WP_ / 4) + col4] = src[idx];
    }
    __syncthreads();

    // ---- Phase 2: row-wise inclusive scan (x), float2 per lane ----
    const int wave = tid >> 6, lane = tid & 63;
    for (int r = wave; r < H_; r += 8) {
        float2* p2 = (float2*)(sat + r * WP_);
        float2 v = p2[lane];
        float s  = v.x + v.y;
        #pragma unroll
        for (int d = 1; d < 64; d <<= 1) {
            float t = __shfl_up(s, d);
            if (lane >= d) s += t;
        }
        float excl = s - (v.x + v.y);
        p2[lane] = make_float2(excl + v.x, excl + v.x + v.y);
    }
    __syncthreads();

    // ---- Phase 3a: quarter-column inclusive scans (chain length 32) ----
    {
        const int qy = tid >> 7;        // 0..3
        const int x  = tid & 127;
        float acc = 0.f;
        #pragma unroll
        for (int j = 0; j < 32; ++j) {
            const int y = qy * 32 + j;
            acc += sat[y * WP_ + x];
            sat[y * WP_ + x] = acc;
        }
        qt[qy][x] = acc;                // quarter total
    }
    __syncthreads();

    // ---- Phase 3b: exclusive prefix of quarter totals (per column) ----
    if (tid < W_) {
        const int x = tid;
        float t0 = qt[0][x], t1 = qt[1][x], t2 = qt[2][x];
        qt[1][x] = t0;
        qt[2][x] = t0 + t1;
        qt[3][x] = t0 + t1 + t2;
    }
    __syncthreads();

    // ---- Phase 3c: parallel fixup for quarters 1..3 (no serial chain) ----
    #pragma unroll
    for (int j = 0; j < 24; ++j) {
        const int e = j * 512 + tid;    // 0..12287
        const int y = 32 + (e >> 7);
        const int x = e & 127;
        sat[y * WP_ + x] += qt[y >> 5][x];
    }
    __syncthreads();

    // ---- Phase 4: gather all (q, bin) for this (b, c) ----
    const int* rb = rois + (size_t)b * Q_ * 5;
    for (int t = tid; t < Q_ * 49; t += 512) {
        const int q   = t / 49;
        const int bin = t - q * 49;
        const int oy  = bin / 7;
        const int ox  = bin - oy * 7;

        const int x1 = rb[q * 5 + 1];
        const int y1 = rb[q * 5 + 2];
        const int Lx = rb[q * 5 + 3] - x1;
        const int Ly = rb[q * 5 + 4] - y1;

        const int ys = y1 + (oy * Ly) / 7;               // floor
        const int ye = y1 + ((oy + 1) * Ly + 6) / 7;     // ceil
        const int xs = x1 + (ox * Lx) / 7;               // floor
        const int xe = x1 + ((ox + 1) * Lx + 6) / 7;     // ceil

        const float s11 = sat[(ye - 1) * WP_ + (xe - 1)];
        const float s01 = (ys > 0) ? sat[(ys - 1) * WP_ + (xe - 1)] : 0.f;
        const float s10 = (xs > 0) ? sat[(ye - 1) * WP_ + (xs - 1)] : 0.f;
        const float s00 = (ys > 0 && xs > 0) ? sat[(ys - 1) * WP_ + (xs - 1)] : 0.f;

        const float area = (float)((ye - ys) * (xe - xs));
        out[(((size_t)(b * Q_ + q)) * C_ + c) * 49 + bin] =
            (s11 - s01 - s10 + s00) / area;
    }
}

extern "C" void kernel_launch(void* const* d_in, const int* in_sizes, int n_in,
                              void* d_out, int out_size, void* d_ws, size_t ws_size,
                              hipStream_t stream) {
    const float* x    = (const float*)d_in[0];
    const int*   rois = (const int*)d_in[1];
    float*       outp = (float*)d_out;

    roipool_kernel<<<B_ * C_, 512, 0, stream>>>((const float4*)x, rois, outp);
}

// Round 8
// 108.136 us; speedup vs baseline: 1.4267x; 1.0984x over previous
//
#include <hip/hip_runtime.h>

#define B_ 4
#define C_ 256
#define H_ 128
#define W_ 128
#define Q_ 100
#define WP_ 132                 // padded row stride in words (132%32=4 -> bank=(4y+x)%32)

// ---------------------------------------------------------------------------
// Single fused kernel. Block = (b, c): one channel 128x128 -> SAT in LDS ->
// all 100*49 outputs. 512 threads (8 waves), LDS 78.8 KB -> 2 blocks/CU.
//  A: per-q bin-edge tables (packed uchar4 in uint), 700 entries.
//  B: fused load + row scan: 2 rows/wave as float4, reg scan + 5 shuffle
//     steps per 32-lane group, one b128 LDS write. (no separate phase 1)
//  C: column scan: 16 octants x 32 float4-strips, b128 register scan;
//     octant totals -> exclusive scan (32 threads) -> b128 fixup.
//  D: gather: 2 packed edge reads + 4 sat reads + v_rcp per bin.
// ---------------------------------------------------------------------------
__global__ __launch_bounds__(512, 4) void roipool_kernel(const float4* __restrict__ x4,
                                                         const int* __restrict__ rois,
                                                         float* __restrict__ out) {
    __shared__ __align__(16) float sat[H_ * WP_];   // 67584 B
    __shared__ float4 ot4[16 * 33];                 // 8448 B octant totals (padded)
    __shared__ unsigned int ebl[Q_ * 7];            // 2800 B packed edges

    const int c   = blockIdx.x & 255;
    const int b   = blockIdx.x >> 8;
    const int tid = threadIdx.x;

    // ---- B: fused global load + row-wise inclusive scan ----
    const float4* src = x4 + (size_t)(b * C_ + c) * (H_ * W_ / 4);
    const int wv = tid >> 6, ln = tid & 63;
    const int xl = ln & 31;          // float4 column 0..31
    #pragma unroll
    for (int i = 0; i < 8; ++i) {
        const int r = wv * 16 + i * 2 + (ln >> 5);
        float4 v = src[wv * 512 + i * 64 + ln];     // == r*32 + xl (contiguous)
        float s = v.x + v.y + v.z + v.w;
        float run = s;
        #pragma unroll
        for (int d = 1; d < 32; d <<= 1) {
            float t = __shfl_up(run, d);
            if (xl >= d) run += t;
        }
        const float excl = run - s;
        float4 o;
        o.x = excl + v.x;
        o.y = o.x + v.y;
        o.z = o.y + v.z;
        o.w = o.z + v.w;
        ((float4*)(sat + r * WP_))[xl] = o;
    }

    // ---- A: per-(q,k) packed edge table (independent of sat) ----
    const int* rbase = rois + (size_t)b * Q_ * 5;
    for (int t = tid; t < Q_ * 7; t += 512) {
        const int q = t / 7;
        const int k = t - q * 7;
        const int* rb = rbase + q * 5;
        const int x1 = rb[1], y1 = rb[2];
        const int Lx = rb[3] - x1, Ly = rb[4] - y1;
        const unsigned int ys = y1 + (k * Ly) / 7;
        const unsigned int ye = y1 + ((k + 1) * Ly + 6) / 7;
        const unsigned int xs = x1 + (k * Lx) / 7;
        const unsigned int xe = x1 + ((k + 1) * Lx + 6) / 7;
        ebl[t] = ys | (ye << 8) | (xs << 16) | (xe << 24);
    }
    __syncthreads();

    // ---- C1: octant column scans (16 octants x 32 strips, float4) ----
    {
        float4* s4 = (float4*)sat;
        const int oct = tid >> 5;        // 0..15
        const int stp = tid & 31;        // 0..31
        float4 acc = make_float4(0.f, 0.f, 0.f, 0.f);
        #pragma unroll
        for (int j = 0; j < 8; ++j) {
            const int y = oct * 8 + j;
            float4 v = s4[y * 33 + stp];
            acc.x += v.x; acc.y += v.y; acc.z += v.z; acc.w += v.w;
            s4[y * 33 + stp] = acc;
        }
        ot4[oct * 33 + stp] = acc;
    }
    __syncthreads();

    // ---- C2: exclusive scan of octant totals per strip (32 threads) ----
    if (tid < 32) {
        float4 run = make_float4(0.f, 0.f, 0.f, 0.f);
        #pragma unroll
        for (int k = 0; k < 16; ++k) {
            float4 v = ot4[k * 33 + tid];
            ot4[k * 33 + tid] = run;
            run.x += v.x; run.y += v.y; run.z += v.z; run.w += v.w;
        }
    }
    __syncthreads();

    // ---- C3: fixup (octants 1..15) ----
    {
        float4* s4 = (float4*)sat;
        #pragma unroll
        for (int j = 0; j < 8; ++j) {
            const int f = j * 512 + tid;     // valid float4 index 0..4095
            const int y = f >> 5;
            const int oc = y >> 3;
            const int st = f & 31;
            if (oc > 0) {
                float4 off = ot4[oc * 33 + st];
                float4 v = s4[y * 33 + st];
                v.x += off.x; v.y += off.y; v.z += off.z; v.w += off.w;
                s4[y * 33 + st] = v;
            }
        }
    }
    __syncthreads();

    // ---- D: gather all (q, bin) for this (b, c) ----
    float* ob = out + (size_t)(b * Q_) * (C_ * 49) + (size_t)c * 49;
    for (int t = tid; t < Q_ * 49; t += 512) {
        const int q   = t / 49;
        const int bin = t - q * 49;
        const int oy  = bin / 7;
        const int ox  = bin - oy * 7;

        const unsigned int ey = ebl[q * 7 + oy];
        const unsigned int ex = ebl[q * 7 + ox];
        const int ys = ey & 255;
        const int ye = (ey >> 8) & 255;
        const int xs = (ex >> 16) & 255;
        const int xe = ex >> 24;

        const float s11 = sat[(ye - 1) * WP_ + (xe - 1)];
        const float s01 = (ys > 0) ? sat[(ys - 1) * WP_ + (xe - 1)] : 0.f;
        const float s10 = (xs > 0) ? sat[(ye - 1) * WP_ + (xs - 1)] : 0.f;
        const float s00 = (ys > 0 && xs > 0) ? sat[(ys - 1) * WP_ + (xs - 1)] : 0.f;

        const float inv = __builtin_amdgcn_rcpf((float)((ye - ys) * (xe - xs)));
        ob[(size_t)q * (C_ * 49) + bin] = (s11 - s01 - s10 + s00) * inv;
    }
}

extern "C" void kernel_launch(void* const* d_in, const int* in_sizes, int n_in,
                              void* d_out, int out_size, void* d_ws, size_t ws_size,
                              hipStream_t stream) {
    const float* x    = (const float*)d_in[0];
    const int*   rois = (const int*)d_in[1];
    float*       outp = (float*)d_out;

    roipool_kernel<<<B_ * C_, 512, 0, stream>>>((const float4*)x, rois, outp);
}

// Round 9
// 106.249 us; speedup vs baseline: 1.4521x; 1.0178x over previous
//
#include <hip/hip_runtime.h>

#define B_ 4
#define C_ 256
#define H_ 128
#define W_ 128
#define Q_ 100
#define WROW 132            // words per SAT row (132%32=4 -> bank spread (4y+x)%32)
#define NROW 129            // row 0 is the zero row; image row r -> SAT row r+1

// Inclusive +-scan within each 32-lane group, pure VALU (DPP), no LDS ops.
__device__ __forceinline__ float dpp_scan32(float s) {
    int t;
    t = __builtin_amdgcn_update_dpp(0, __float_as_int(s), 0x111, 0xf, 0xf, true); // row_shr:1
    s += __int_as_float(t);
    t = __builtin_amdgcn_update_dpp(0, __float_as_int(s), 0x112, 0xf, 0xf, true); // row_shr:2
    s += __int_as_float(t);
    t = __builtin_amdgcn_update_dpp(0, __float_as_int(s), 0x114, 0xf, 0xf, true); // row_shr:4
    s += __int_as_float(t);
    t = __builtin_amdgcn_update_dpp(0, __float_as_int(s), 0x118, 0xf, 0xf, true); // row_shr:8
    s += __int_as_float(t);
    t = __builtin_amdgcn_update_dpp(0, __float_as_int(s), 0x142, 0xa, 0xf, true); // bcast15 -> rows 1,3
    s += __int_as_float(t);
    return s;
}

// ---------------------------------------------------------------------------
// Block = (b, c). 512 threads, LDS 79.4 KB -> 2 blocks/CU.
//  A : packed bin-edge table (700 u32).
//  B': vertical-strip load (8x dwordx4) + column scan in REGISTERS
//      (scans commute: colscan before rowscan), one b128 write per row,
//      octant totals -> ot4.
//  C2: exclusive scan of octant totals per strip (32 threads).
//  R : row scan with fused octant fixup: b128 read + ot4 read + add,
//      DPP scan (VALU pipe), b128 write. No ds_bpermute anywhere.
//  D : guard-free gather: zero row/col inside sat, 4 unconditional reads.
// ---------------------------------------------------------------------------
__global__ __launch_bounds__(512, 4) void roipool_kernel(const float4* __restrict__ x4,
                                                         const int* __restrict__ rois,
                                                         float* __restrict__ out) {
    __shared__ __align__(16) float sat[NROW * WROW];    // 68112 B
    __shared__ float4 ot4[16 * 33];                     // 8448 B
    __shared__ unsigned int ebl[Q_ * 7];                // 2800 B

    const int c   = blockIdx.x & 255;
    const int b   = blockIdx.x >> 8;
    const int tid = threadIdx.x;

    // Zero row 0 (words 0..131) and zero column (word 3 of rows 1..128).
    if (tid < WROW) sat[tid] = 0.f;
    else if (tid < WROW + 128) sat[(tid - WROW + 1) * WROW + 3] = 0.f;

    // ---- A: packed edges: ys | ye<<8 | (xs+3)<<16 | (xe+3)<<24 ----
    const int* rbase = rois + b * Q_ * 5;
    for (int t = tid; t < Q_ * 7; t += 512) {
        const int q = t / 7;
        const int k = t - q * 7;
        const int* rb = rbase + q * 5;
        const int x1 = rb[1], y1 = rb[2];
        const int Lx = rb[3] - x1, Ly = rb[4] - y1;
        const unsigned int ys = y1 + (k * Ly) / 7;
        const unsigned int ye = y1 + ((k + 1) * Ly + 6) / 7;
        const unsigned int xs = x1 + (k * Lx) / 7 + 3;
        const unsigned int xe = x1 + ((k + 1) * Lx + 6) / 7 + 3;
        ebl[t] = ys | (ye << 8) | (xs << 16) | (xe << 24);
    }

    // ---- B': vertical strips, register column scan ----
    {
        const int oct = tid >> 5;        // 0..15 (8 image rows each)
        const int stp = tid & 31;        // float4 column 0..31
        const float4* src = x4 + (size_t)(b * C_ + c) * (H_ * W_ / 4);
        float4 v[8];
        #pragma unroll
        for (int j = 0; j < 8; ++j)
            v[j] = src[(oct * 8 + j) * 32 + stp];
        float4 acc = v[0];
        #pragma unroll
        for (int j = 0; j < 8; ++j) {
            if (j) { acc.x += v[j].x; acc.y += v[j].y; acc.z += v[j].z; acc.w += v[j].w; }
            ((float4*)(sat + (oct * 8 + j + 1) * WROW + 4))[stp] = acc;
        }
        ot4[oct * 33 + stp] = acc;       // octant total
    }
    __syncthreads();

    // ---- C2: exclusive scan of octant totals per strip ----
    if (tid < 32) {
        float4 run = make_float4(0.f, 0.f, 0.f, 0.f);
        #pragma unroll
        for (int k = 0; k < 16; ++k) {
            float4 v = ot4[k * 33 + tid];
            ot4[k * 33 + tid] = run;
            run.x += v.x; run.y += v.y; run.z += v.z; run.w += v.w;
        }
    }
    __syncthreads();

    // ---- R: row scan with fused octant fixup (DPP, no LDS shuffles) ----
    {
        const int wv = tid >> 6, ln = tid & 63;
        const int xl = ln & 31;
        #pragma unroll
        for (int i = 0; i < 8; ++i) {
            const int r = wv * 16 + i * 2 + (ln >> 5);    // image row
            float4* p = (float4*)(sat + (r + 1) * WROW + 4);
            float4 v = p[xl];
            float4 off = ot4[(r >> 3) * 33 + xl];
            v.x += off.x; v.y += off.y; v.z += off.z; v.w += off.w;
            float s = v.x + v.y + v.z + v.w;
            float run = dpp_scan32(s);
            const float excl = run - s;
            float4 o;
            o.x = excl + v.x;
            o.y = o.x + v.y;
            o.z = o.y + v.z;
            o.w = o.z + v.w;
            p[xl] = o;
        }
    }
    __syncthreads();

    // ---- D: guard-free gather ----
    float* ob = out + (size_t)(b * Q_) * (C_ * 49) + (size_t)c * 49;
    for (int t = tid; t < Q_ * 49; t += 512) {
        const int q   = t / 49;
        const int bin = t - q * 49;
        const int oy  = bin / 7;
        const int ox  = bin - oy * 7;

        const unsigned int ey = ebl[q * 7 + oy];
        const unsigned int ex = ebl[q * 7 + ox];
        const int ys  = ey & 255;
        const int ye  = (ey >> 8) & 255;
        const int xs3 = (ex >> 16) & 255;
        const int xe3 = ex >> 24;

        const int ylo = ys * WROW;
        const int yhi = ye * WROW;
        const float s11 = sat[yhi + xe3];
        const float s01 = sat[ylo + xe3];
        const float s10 = sat[yhi + xs3];
        const float s00 = sat[ylo + xs3];

        const float inv = __builtin_amdgcn_rcpf((float)((ye - ys) * (xe3 - xs3)));
        ob[(size_t)q * (C_ * 49) + bin] = ((s11 - s01) - (s10 - s00)) * inv;
    }
}

extern "C" void kernel_launch(void* const* d_in, const int* in_sizes, int n_in,
                              void* d_out, int out_size, void* d_ws, size_t ws_size,
                              hipStream_t stream) {
    const float* x    = (const float*)d_in[0];
    const int*   rois = (const int*)d_in[1];
    float*       outp = (float*)d_out;

    roipool_kernel<<<B_ * C_, 512, 0, stream>>>((const float4*)x, rois, outp);
}